// Round 3
// baseline (800.198 us; speedup 1.0000x reference)
//
#include <hip/hip_runtime.h>
#include <hip/hip_bf16.h>
#include <hip/hip_fp16.h>
#include <math.h>

constexpr int N_NODES = 50000;
constexpr int N_EDGES = 850000;
constexpr int HDIM = 128;   // H*D

// ---------------- CSR build: counting sort partitioned by dst range ----------------
constexpr int NB_SORT = 64;
constexpr int RANGE = (N_NODES + NB_SORT - 1) / NB_SORT;  // 782 nodes/block

// Each block owns node range [lo,hi); streams all dst, LDS histogram -> deg.
__global__ void k_deg(const int* __restrict__ dst, int* __restrict__ deg) {
    __shared__ int hist[RANGE];
    int tid = threadIdx.x;
    int lo = blockIdx.x * RANGE;
    int hi = min(lo + RANGE, N_NODES);
    for (int j = tid; j < RANGE; j += 1024) hist[j] = 0;
    __syncthreads();
    const int4* d4p = reinterpret_cast<const int4*>(dst);
    for (int i4 = tid; i4 < N_EDGES / 4; i4 += 1024) {
        int4 d4 = d4p[i4];
        int d[4] = {d4.x, d4.y, d4.z, d4.w};
#pragma unroll
        for (int k = 0; k < 4; k++)
            if (d[k] >= lo && d[k] < hi) atomicAdd(&hist[d[k] - lo], 1);
    }
    __syncthreads();
    for (int j = tid; j + lo < hi; j += 1024) deg[lo + j] = hist[j];
}

// ---------------- multi-block exclusive scan of deg -> rowstart ----------------
constexpr int SCAN_B = 256;
constexpr int SCAN_G = (N_NODES + SCAN_B - 1) / SCAN_B;  // 196

__device__ __forceinline__ int block_excl_scan_256(int v, int tid) {
    __shared__ int ws[4];
    int lane = tid & 63, w = tid >> 6;
    int inc = v;
#pragma unroll
    for (int off = 1; off < 64; off <<= 1) {
        int t = __shfl_up(inc, off, 64);
        if (lane >= off) inc += t;
    }
    if (lane == 63) ws[w] = inc;
    __syncthreads();
    int woff = 0;
    for (int j = 0; j < w; j++) woff += ws[j];
    return woff + inc - v;
}

__global__ void k_scan_part(const int* __restrict__ deg, int* __restrict__ partial) {
    int i = blockIdx.x * SCAN_B + threadIdx.x;
    int v = (i < N_NODES) ? deg[i] : 0;
#pragma unroll
    for (int off = 1; off < 64; off <<= 1) v += __shfl_xor(v, off, 64);
    __shared__ int ws[4];
    if ((threadIdx.x & 63) == 0) ws[threadIdx.x >> 6] = v;
    __syncthreads();
    if (threadIdx.x == 0) partial[blockIdx.x] = ws[0] + ws[1] + ws[2] + ws[3];
}

__global__ void k_scan_mid(int* __restrict__ partial, int* __restrict__ rowstart) {
    int t = threadIdx.x;
    int v = (t < SCAN_G) ? partial[t] : 0;
    int excl = block_excl_scan_256(v, t);
    if (t < SCAN_G) partial[t] = excl;
    if (t == 0) rowstart[N_NODES] = N_EDGES;
}

__global__ void k_scan_apply(const int* __restrict__ deg, const int* __restrict__ partial,
                             int* __restrict__ rowstart) {
    int i = blockIdx.x * SCAN_B + threadIdx.x;
    int v = (i < N_NODES) ? deg[i] : 0;
    int excl = block_excl_scan_256(v, threadIdx.x);
    if (i < N_NODES) rowstart[i] = partial[blockIdx.x] + excl;
}

// Scatter: each block re-streams dst; LDS cursors; writes land in its contiguous region.
__global__ void k_scatter2(const int* __restrict__ src, const int* __restrict__ dst,
                           const int* __restrict__ rowstart, int* __restrict__ esrc) {
    __shared__ int cur[RANGE];
    int tid = threadIdx.x;
    int lo = blockIdx.x * RANGE;
    int hi = min(lo + RANGE, N_NODES);
    for (int j = tid; j + lo < hi; j += 1024) cur[j] = rowstart[lo + j];
    __syncthreads();
    const int4* d4p = reinterpret_cast<const int4*>(dst);
    for (int i4 = tid; i4 < N_EDGES / 4; i4 += 1024) {
        int4 d4 = d4p[i4];
        int d[4] = {d4.x, d4.y, d4.z, d4.w};
#pragma unroll
        for (int k = 0; k < 4; k++) {
            if (d[k] >= lo && d[k] < hi) {
                int p = atomicAdd(&cur[d[k] - lo], 1);
                esrc[p] = src[i4 * 4 + k];
            }
        }
    }
}

// ---------------- GEMM: feat_h = act(in) @ W (fp16 out) + fused el/er epilogue ----------------
// mode 0: in-row n = embed[xidx[n]]. mode 1: in-row n = elu(h[n]*bnsc + bnsh).
__global__ void k_gemm(const float* __restrict__ h, const int* __restrict__ xidx,
                       const float* __restrict__ embed, const float* __restrict__ W,
                       __half* __restrict__ feat_h, const float* __restrict__ bnsc,
                       const float* __restrict__ bnsh, const float* __restrict__ al,
                       const float* __restrict__ ar, float* __restrict__ el,
                       float* __restrict__ er, int mode) {
    __shared__ __align__(16) float hsT[128][36];
    int tid = threadIdx.x;
    int nbase = blockIdx.x * 32;
    for (int i = tid; i < 32 * 128; i += 256) {
        int r = i >> 7, c = i & 127;
        int n = nbase + r;
        float v = 0.f;
        if (n < N_NODES) {
            if (mode == 0) {
                v = embed[xidx[n] * HDIM + c];
            } else {
                v = h[n * HDIM + c] * bnsc[c] + bnsh[c];
                v = (v > 0.f) ? v : expm1f(v);
            }
        }
        hsT[c][r] = v;
    }
    __syncthreads();
    int c4 = (tid & 31) * 4;  // 4 cols, all within one head (c4 % 4 == 0, head span 32)
    int n4 = (tid >> 5) * 4;
    float acc[4][4] = {};
#pragma unroll 4
    for (int k = 0; k < 128; k++) {
        float4 wv4 = *reinterpret_cast<const float4*>(&W[k * HDIM + c4]);
        float4 hv4 = *reinterpret_cast<const float4*>(&hsT[k][n4]);
        float wv[4] = {wv4.x, wv4.y, wv4.z, wv4.w};
        float hh[4] = {hv4.x, hv4.y, hv4.z, hv4.w};
#pragma unroll
        for (int i = 0; i < 4; i++)
#pragma unroll
            for (int j = 0; j < 4; j++) acc[i][j] += hh[i] * wv[j];
    }
    // store fp16 feat
#pragma unroll
    for (int i = 0; i < 4; i++) {
        int n = nbase + n4 + i;
        if (n < N_NODES) {
            __half2* p = reinterpret_cast<__half2*>(&feat_h[n * HDIM + c4]);
            p[0] = __floats2half2_rn(acc[i][0], acc[i][1]);
            p[1] = __floats2half2_rn(acc[i][2], acc[i][3]);
        }
    }
    // fused attention coefficients: el/er = sum_d feat*al / feat*ar per (node, head).
    // Thread's 4 cols live in head c4>>5; reduce partials over the 8 lanes sharing
    // (row group, head) via shfl_xor 1,2,4.
    float4 alv = *reinterpret_cast<const float4*>(&al[c4]);
    float4 arv = *reinterpret_cast<const float4*>(&ar[c4]);
    float pl[4], pr[4];
#pragma unroll
    for (int i = 0; i < 4; i++) {
        pl[i] = acc[i][0] * alv.x + acc[i][1] * alv.y + acc[i][2] * alv.z + acc[i][3] * alv.w;
        pr[i] = acc[i][0] * arv.x + acc[i][1] * arv.y + acc[i][2] * arv.z + acc[i][3] * arv.w;
    }
#pragma unroll
    for (int off = 1; off < 8; off <<= 1)
#pragma unroll
        for (int i = 0; i < 4; i++) {
            pl[i] += __shfl_xor(pl[i], off, 64);
            pr[i] += __shfl_xor(pr[i], off, 64);
        }
    int lane = tid & 63;
    if ((lane & 7) == 0) {
        int head = c4 >> 5;
#pragma unroll
        for (int i = 0; i < 4; i++) {
            int n = nbase + n4 + i;
            if (n < N_NODES) {
                el[n * 4 + head] = pl[i];
                er[n * 4 + head] = pr[i];
            }
        }
    }
}

// ---------------- aggregation: one wave per dst node ----------------
__global__ void k_aggregate(const __half* __restrict__ feat_h, const float* __restrict__ el,
                            const float* __restrict__ er, const int* __restrict__ rowstart,
                            const int* __restrict__ esrc, const float* __restrict__ snorm_n,
                            float* __restrict__ h, const float* __restrict__ bnsc,
                            const float* __restrict__ bnsh, int layer) {
    int v = (blockIdx.x * blockDim.x + threadIdx.x) >> 6;
    int lane = threadIdx.x & 63;
    if (v >= N_NODES) return;
    int head = lane >> 4;
    float erv = er[v * 4 + head];
    int e0 = rowstart[v], e1 = rowstart[v + 1];
    float s = 0.f, a0 = 0.f, a1 = 0.f;
    const __half2* fh = reinterpret_cast<const __half2*>(feat_h);
#pragma unroll 4
    for (int i = e0; i < e1; i++) {
        int sidx = esrc[i];
        float e = el[sidx * 4 + head] + erv;
        e = fmaxf(e, 0.f) + 0.2f * fminf(e, 0.f);  // leaky_relu
        float w = __expf(e);
        float2 f = __half22float2(fh[sidx * 64 + lane]);
        s += w;
        a0 = fmaf(f.x, w, a0);
        a1 = fmaf(f.y, w, a1);
    }
    float inv = 1.f / s;  // deg>=1 (self loops)
    a0 *= inv; a1 *= inv;
    int c = lane * 2;
    if (layer > 0) {
        float2 hr = *reinterpret_cast<const float2*>(&h[v * HDIM + c]);
        float2 sc = *reinterpret_cast<const float2*>(&bnsc[c]);
        float2 sh = *reinterpret_cast<const float2*>(&bnsh[c]);
        float r0 = hr.x * sc.x + sh.x; r0 = (r0 > 0.f) ? r0 : expm1f(r0);
        float r1 = hr.y * sc.y + sh.y; r1 = (r1 > 0.f) ? r1 : expm1f(r1);
        a0 += r0; a1 += r1;
        a0 = (a0 > 0.f) ? a0 : expm1f(a0);  // GATConv activation (layers>0)
        a1 = (a1 > 0.f) ? a1 : expm1f(a1);
    }
    float sn = snorm_n[v];
    *reinterpret_cast<float2*>(&h[v * HDIM + c]) = make_float2(a0 * sn, a1 * sn);
}

// ---------------- BatchNorm stats ----------------
__global__ void k_bn_stats(const float* __restrict__ h, double* __restrict__ sums) {
    int c = threadIdx.x;
    double s = 0.0, s2 = 0.0;
    for (int r = blockIdx.x; r < N_NODES; r += gridDim.x) {
        float v = h[r * HDIM + c];
        s += v;
        s2 += (double)v * v;
    }
    atomicAdd(&sums[c], s);
    atomicAdd(&sums[128 + c], s2);
}

__global__ void k_bn_final(const double* __restrict__ sums, const float* __restrict__ gamma,
                           const float* __restrict__ beta, float* __restrict__ scale,
                           float* __restrict__ shift) {
    int c = threadIdx.x;
    double mu = sums[c] / N_NODES;
    double var = sums[128 + c] / N_NODES - mu * mu;
    float sc = gamma[c] * rsqrtf((float)var + 1e-5f);
    scale[c] = sc;
    shift[c] = beta[c] - (float)mu * sc;
}

// ---------------- classifier ----------------
__global__ void k_classifier(const float* __restrict__ h, const float* __restrict__ W1,
                             const float* __restrict__ b1, const float* __restrict__ W2,
                             const float* __restrict__ b2, const float* __restrict__ bnsc,
                             const float* __restrict__ bnsh, float* __restrict__ out) {
    __shared__ float hs[16][128];
    int tid = threadIdx.x;
    int nbase = blockIdx.x * 16;
    for (int i = tid; i < 16 * 128; i += 256) {
        int r = i >> 7, c = i & 127;
        int n = nbase + r;
        float v = 0.f;
        if (n < N_NODES) {
            v = h[n * HDIM + c] * bnsc[c] + bnsh[c];
            v = (v > 0.f) ? v : expm1f(v);
        }
        hs[r][c] = v;
    }
    __syncthreads();
    int j = tid & 63;
    int g = tid >> 6;
    float bj = b1[j];
    float acc[4] = {bj, bj, bj, bj};
    for (int k = 0; k < 128; k++) {
        float w = W1[k * 64 + j];
#pragma unroll
        for (int i = 0; i < 4; i++) acc[i] += hs[g * 4 + i][k] * w;
    }
    float w20 = W2[j * 2], w21 = W2[j * 2 + 1];
    float res[8];
#pragma unroll
    for (int i = 0; i < 4; i++) {
        float hid = fmaxf(acc[i], 0.f);
        res[2 * i] = hid * w20;
        res[2 * i + 1] = hid * w21;
    }
#pragma unroll
    for (int off = 1; off < 64; off <<= 1)
#pragma unroll
        for (int i = 0; i < 8; i++) res[i] += __shfl_xor(res[i], off, 64);
    if (j < 8) {
        int n = nbase + g * 4 + (j >> 1);
        if (n < N_NODES) out[n * 2 + (j & 1)] = res[j] + b2[j & 1];
    }
}

// ----------------------------------------------------------------
extern "C" void kernel_launch(void* const* d_in, const int* in_sizes, int n_in,
                              void* d_out, int out_size, void* d_ws, size_t ws_size,
                              hipStream_t stream) {
    const int* x = (const int*)d_in[0];
    const int* src = (const int*)d_in[1];
    const int* dst = (const int*)d_in[2];
    const float* snorm_n = (const float*)d_in[3];
    const float* embed = (const float*)d_in[5];
    const float* Ws[3] = {(const float*)d_in[6], (const float*)d_in[11], (const float*)d_in[16]};
    const float* als[3] = {(const float*)d_in[7], (const float*)d_in[12], (const float*)d_in[17]};
    const float* ars[3] = {(const float*)d_in[8], (const float*)d_in[13], (const float*)d_in[18]};
    const float* gms[3] = {(const float*)d_in[9], (const float*)d_in[14], (const float*)d_in[19]};
    const float* bts[3] = {(const float*)d_in[10], (const float*)d_in[15], (const float*)d_in[20]};
    const float* cls1_w = (const float*)d_in[21];
    const float* cls1_b = (const float*)d_in[22];
    const float* cls2_w = (const float*)d_in[23];
    const float* cls2_b = (const float*)d_in[24];
    float* out = (float*)d_out;

    char* ws = (char*)d_ws;
    size_t off = 0;
    auto alloc = [&](size_t bytes) {
        void* p = ws + off;
        off = (off + bytes + 255) & ~(size_t)255;
        return p;
    };
    float* h = (float*)alloc((size_t)N_NODES * HDIM * 4);
    __half* feat_h = (__half*)alloc((size_t)N_NODES * HDIM * 2);
    float* el = (float*)alloc((size_t)N_NODES * 4 * 4);
    float* er = (float*)alloc((size_t)N_NODES * 4 * 4);
    int* deg = (int*)alloc((size_t)N_NODES * 4);
    int* rowstart = (int*)alloc((size_t)(N_NODES + 1) * 4);
    int* partial = (int*)alloc((size_t)SCAN_G * 4);
    int* esrc = (int*)alloc((size_t)N_EDGES * 4);
    double* bn_sums = (double*)alloc(256 * 8);
    float* bn_scale = (float*)alloc(128 * 4);
    float* bn_shift = (float*)alloc(128 * 4);
    (void)ws_size; (void)in_sizes; (void)n_in; (void)out_size;

    // CSR by destination: counting sort, dst-range-partitioned (no global atomics)
    k_deg<<<NB_SORT, 1024, 0, stream>>>(dst, deg);
    k_scan_part<<<SCAN_G, SCAN_B, 0, stream>>>(deg, partial);
    k_scan_mid<<<1, SCAN_B, 0, stream>>>(partial, rowstart);
    k_scan_apply<<<SCAN_G, SCAN_B, 0, stream>>>(deg, partial, rowstart);
    k_scatter2<<<NB_SORT, 1024, 0, stream>>>(src, dst, rowstart, esrc);

    for (int L = 0; L < 3; L++) {
        k_gemm<<<(N_NODES + 31) / 32, 256, 0, stream>>>(h, x, embed, Ws[L], feat_h,
                                                        bn_scale, bn_shift, als[L], ars[L],
                                                        el, er, L == 0 ? 0 : 1);
        k_aggregate<<<(N_NODES + 3) / 4, 256, 0, stream>>>(feat_h, el, er, rowstart, esrc,
                                                           snorm_n, h, bn_scale, bn_shift, L);
        hipMemsetAsync(bn_sums, 0, 256 * 8, stream);
        k_bn_stats<<<1024, 128, 0, stream>>>(h, bn_sums);
        k_bn_final<<<1, 128, 0, stream>>>(bn_sums, gms[L], bts[L], bn_scale, bn_shift);
    }

    k_classifier<<<(N_NODES + 15) / 16, 256, 0, stream>>>(h, cls1_w, cls1_b, cls2_w, cls2_b,
                                                          bn_scale, bn_shift, out);
}

// Round 4
// 529.339 us; speedup vs baseline: 1.5117x; 1.5117x over previous
//
#include <hip/hip_runtime.h>
#include <hip/hip_bf16.h>
#include <hip/hip_fp16.h>
#include <math.h>

constexpr int N_NODES = 50000;
constexpr int N_EDGES = 850000;
constexpr int HDIM = 128;   // H*D

// ---------------- CSR build: two-phase bucket sort ----------------
constexpr int NB2 = 128;                                // buckets
constexpr int RANGE2 = (N_NODES + NB2 - 1) / NB2;       // 391 nodes/bucket
constexpr int CAP = 8192;                               // bucket capacity (avg 6641, 6-sigma safe)
constexpr int CHUNK = 8192;                             // edges per phase-A block
constexpr int GA = (N_EDGES + CHUNK - 1) / CHUNK;       // 104 blocks

// Phase A: each block owns a contiguous edge chunk; LDS histogram by bucket;
// reserve contiguous sub-ranges via one global atomic per (block,bucket); scatter packed recs.
__global__ void k_partA(const int* __restrict__ src, const int* __restrict__ dst,
                        int* __restrict__ g_cursor, unsigned* __restrict__ bucket) {
    __shared__ int hist[NB2];
    int tid = threadIdx.x;
    int e0 = blockIdx.x * CHUNK;
    int e1 = min(e0 + CHUNK, N_EDGES);
    if (tid < NB2) hist[tid] = 0;
    __syncthreads();
    for (int i = e0 + tid; i < e1; i += 1024) {
        int d = dst[i];
        atomicAdd(&hist[d / RANGE2], 1);
    }
    __syncthreads();
    int base = 0;
    if (tid < NB2) base = atomicAdd(&g_cursor[tid], hist[tid]);
    __syncthreads();
    if (tid < NB2) hist[tid] = base;  // hist now = running cursor
    __syncthreads();
    for (int i = e0 + tid; i < e1; i += 1024) {
        int d = dst[i];
        int s = src[i];
        int b = d / RANGE2;
        int p = atomicAdd(&hist[b], 1);
        bucket[b * CAP + p] = (unsigned)s | ((unsigned)(d - b * RANGE2) << 16);
    }
}

// Phase B: one block per bucket. Contiguous read of its edges; LDS hist+scan over 391
// local nodes; write rowstart; scatter esrc into the bucket's contiguous global region.
__global__ void k_partB(const unsigned* __restrict__ bucket, const int* __restrict__ cnts,
                        int* __restrict__ rowstart, int* __restrict__ esrc) {
    __shared__ int cnt_s[NB2];
    __shared__ int hist[RANGE2];
    __shared__ int lcur[RANGE2];
    __shared__ int wsum[7];
    int b = blockIdx.x, tid = threadIdx.x;
    int lo = b * RANGE2;
    int myCount = cnts[b];
    // exclusive scan of bucket counts -> global base of this bucket's CSR region
    if (tid < NB2) cnt_s[tid] = cnts[tid];
    __syncthreads();
    for (int off = 1; off < NB2; off <<= 1) {
        int t = (tid < NB2 && tid >= off) ? cnt_s[tid - off] : 0;
        __syncthreads();
        if (tid < NB2) cnt_s[tid] += t;
        __syncthreads();
    }
    int base = cnt_s[b] - myCount;
    // local histogram
    for (int j = tid; j < RANGE2; j += 1024) hist[j] = 0;
    __syncthreads();
    const unsigned* my = bucket + (size_t)b * CAP;
    for (int i = tid; i < myCount; i += 1024) atomicAdd(&hist[my[i] >> 16], 1);
    __syncthreads();
    // scan 391 entries (7 waves incl. padding)
    int v = 0;
    if (tid < 448) v = (tid < RANGE2) ? hist[tid] : 0;
    int inc = v;
    int lane = tid & 63;
#pragma unroll
    for (int off = 1; off < 64; off <<= 1) {
        int t = __shfl_up(inc, off, 64);
        if (lane >= off) inc += t;
    }
    if (tid < 448 && lane == 63) wsum[tid >> 6] = inc;
    __syncthreads();
    if (tid < RANGE2) {
        int woff = 0;
        for (int w = 0; w < (tid >> 6); w++) woff += wsum[w];
        int excl = woff + inc - v;
        lcur[tid] = excl;
        int node = lo + tid;
        if (node < N_NODES) rowstart[node] = base + excl;
    }
    if (b == 0 && tid == 0) rowstart[N_NODES] = N_EDGES;
    __syncthreads();
    // scatter into contiguous region [base, base+myCount)
    for (int i = tid; i < myCount; i += 1024) {
        unsigned p = my[i];
        int pos = atomicAdd(&lcur[p >> 16], 1);
        esrc[base + pos] = (int)(p & 0xFFFFu);
    }
}

// ---------------- GEMM: feat_h = act(in) @ W (fp16 out) + fused el/er epilogue ----------------
// mode 0: in-row n = embed[xidx[n]]. mode 1: in-row n = elu(h[n]*bnsc + bnsh).
__global__ void k_gemm(const float* __restrict__ h, const int* __restrict__ xidx,
                       const float* __restrict__ embed, const float* __restrict__ W,
                       __half* __restrict__ feat_h, const float* __restrict__ bnsc,
                       const float* __restrict__ bnsh, const float* __restrict__ al,
                       const float* __restrict__ ar, float* __restrict__ el,
                       float* __restrict__ er, int mode) {
    __shared__ __align__(16) float hsT[128][36];
    int tid = threadIdx.x;
    int nbase = blockIdx.x * 32;
    for (int i = tid; i < 32 * 128; i += 256) {
        int r = i >> 7, c = i & 127;
        int n = nbase + r;
        float v = 0.f;
        if (n < N_NODES) {
            if (mode == 0) {
                v = embed[xidx[n] * HDIM + c];
            } else {
                v = h[n * HDIM + c] * bnsc[c] + bnsh[c];
                v = (v > 0.f) ? v : expm1f(v);
            }
        }
        hsT[c][r] = v;
    }
    __syncthreads();
    int c4 = (tid & 31) * 4;  // 4 cols within one head
    int n4 = (tid >> 5) * 4;
    float acc[4][4] = {};
#pragma unroll 4
    for (int k = 0; k < 128; k++) {
        float4 wv4 = *reinterpret_cast<const float4*>(&W[k * HDIM + c4]);
        float4 hv4 = *reinterpret_cast<const float4*>(&hsT[k][n4]);
        float wv[4] = {wv4.x, wv4.y, wv4.z, wv4.w};
        float hh[4] = {hv4.x, hv4.y, hv4.z, hv4.w};
#pragma unroll
        for (int i = 0; i < 4; i++)
#pragma unroll
            for (int j = 0; j < 4; j++) acc[i][j] += hh[i] * wv[j];
    }
#pragma unroll
    for (int i = 0; i < 4; i++) {
        int n = nbase + n4 + i;
        if (n < N_NODES) {
            __half2* p = reinterpret_cast<__half2*>(&feat_h[n * HDIM + c4]);
            p[0] = __floats2half2_rn(acc[i][0], acc[i][1]);
            p[1] = __floats2half2_rn(acc[i][2], acc[i][3]);
        }
    }
    // fused el/er: reduce over the 8 lanes sharing (row group, head)
    float4 alv = *reinterpret_cast<const float4*>(&al[c4]);
    float4 arv = *reinterpret_cast<const float4*>(&ar[c4]);
    float pl[4], pr[4];
#pragma unroll
    for (int i = 0; i < 4; i++) {
        pl[i] = acc[i][0] * alv.x + acc[i][1] * alv.y + acc[i][2] * alv.z + acc[i][3] * alv.w;
        pr[i] = acc[i][0] * arv.x + acc[i][1] * arv.y + acc[i][2] * arv.z + acc[i][3] * arv.w;
    }
#pragma unroll
    for (int off = 1; off < 8; off <<= 1)
#pragma unroll
        for (int i = 0; i < 4; i++) {
            pl[i] += __shfl_xor(pl[i], off, 64);
            pr[i] += __shfl_xor(pr[i], off, 64);
        }
    int lane = tid & 63;
    if ((lane & 7) == 0) {
        int head = c4 >> 5;
#pragma unroll
        for (int i = 0; i < 4; i++) {
            int n = nbase + n4 + i;
            if (n < N_NODES) {
                el[n * 4 + head] = pl[i];
                er[n * 4 + head] = pr[i];
            }
        }
    }
}

// ---------------- aggregation: one wave per dst node ----------------
__global__ void k_aggregate(const __half* __restrict__ feat_h, const float* __restrict__ el,
                            const float* __restrict__ er, const int* __restrict__ rowstart,
                            const int* __restrict__ esrc, const float* __restrict__ snorm_n,
                            float* __restrict__ h, const float* __restrict__ bnsc,
                            const float* __restrict__ bnsh, int layer) {
    int v = (blockIdx.x * blockDim.x + threadIdx.x) >> 6;
    int lane = threadIdx.x & 63;
    if (v >= N_NODES) return;
    int head = lane >> 4;
    float erv = er[v * 4 + head];
    int e0 = rowstart[v], e1 = rowstart[v + 1];
    float s = 0.f, a0 = 0.f, a1 = 0.f;
    const __half2* fh = reinterpret_cast<const __half2*>(feat_h);
#pragma unroll 4
    for (int i = e0; i < e1; i++) {
        int sidx = esrc[i];
        float e = el[sidx * 4 + head] + erv;
        e = fmaxf(e, 0.f) + 0.2f * fminf(e, 0.f);  // leaky_relu
        float w = __expf(e);
        float2 f = __half22float2(fh[sidx * 64 + lane]);
        s += w;
        a0 = fmaf(f.x, w, a0);
        a1 = fmaf(f.y, w, a1);
    }
    float inv = 1.f / s;  // deg>=1 (self loops)
    a0 *= inv; a1 *= inv;
    int c = lane * 2;
    if (layer > 0) {
        float2 hr = *reinterpret_cast<const float2*>(&h[v * HDIM + c]);
        float2 sc = *reinterpret_cast<const float2*>(&bnsc[c]);
        float2 sh = *reinterpret_cast<const float2*>(&bnsh[c]);
        float r0 = hr.x * sc.x + sh.x; r0 = (r0 > 0.f) ? r0 : expm1f(r0);
        float r1 = hr.y * sc.y + sh.y; r1 = (r1 > 0.f) ? r1 : expm1f(r1);
        a0 += r0; a1 += r1;
        a0 = (a0 > 0.f) ? a0 : expm1f(a0);
        a1 = (a1 > 0.f) ? a1 : expm1f(a1);
    }
    float sn = snorm_n[v];
    *reinterpret_cast<float2*>(&h[v * HDIM + c]) = make_float2(a0 * sn, a1 * sn);
}

// ---------------- BatchNorm stats ----------------
__global__ void k_bn_stats(const float* __restrict__ h, double* __restrict__ sums) {
    int c = threadIdx.x;
    double s = 0.0, s2 = 0.0;
    for (int r = blockIdx.x; r < N_NODES; r += gridDim.x) {
        float v = h[r * HDIM + c];
        s += v;
        s2 += (double)v * v;
    }
    atomicAdd(&sums[c], s);
    atomicAdd(&sums[128 + c], s2);
}

__global__ void k_bn_final(const double* __restrict__ sums, const float* __restrict__ gamma,
                           const float* __restrict__ beta, float* __restrict__ scale,
                           float* __restrict__ shift) {
    int c = threadIdx.x;
    double mu = sums[c] / N_NODES;
    double var = sums[128 + c] / N_NODES - mu * mu;
    float sc = gamma[c] * rsqrtf((float)var + 1e-5f);
    scale[c] = sc;
    shift[c] = beta[c] - (float)mu * sc;
}

// ---------------- classifier ----------------
__global__ void k_classifier(const float* __restrict__ h, const float* __restrict__ W1,
                             const float* __restrict__ b1, const float* __restrict__ W2,
                             const float* __restrict__ b2, const float* __restrict__ bnsc,
                             const float* __restrict__ bnsh, float* __restrict__ out) {
    __shared__ float hs[16][128];
    int tid = threadIdx.x;
    int nbase = blockIdx.x * 16;
    for (int i = tid; i < 16 * 128; i += 256) {
        int r = i >> 7, c = i & 127;
        int n = nbase + r;
        float v = 0.f;
        if (n < N_NODES) {
            v = h[n * HDIM + c] * bnsc[c] + bnsh[c];
            v = (v > 0.f) ? v : expm1f(v);
        }
        hs[r][c] = v;
    }
    __syncthreads();
    int j = tid & 63;
    int g = tid >> 6;
    float bj = b1[j];
    float acc[4] = {bj, bj, bj, bj};
    for (int k = 0; k < 128; k++) {
        float w = W1[k * 64 + j];
#pragma unroll
        for (int i = 0; i < 4; i++) acc[i] += hs[g * 4 + i][k] * w;
    }
    float w20 = W2[j * 2], w21 = W2[j * 2 + 1];
    float res[8];
#pragma unroll
    for (int i = 0; i < 4; i++) {
        float hid = fmaxf(acc[i], 0.f);
        res[2 * i] = hid * w20;
        res[2 * i + 1] = hid * w21;
    }
#pragma unroll
    for (int off = 1; off < 64; off <<= 1)
#pragma unroll
        for (int i = 0; i < 8; i++) res[i] += __shfl_xor(res[i], off, 64);
    if (j < 8) {
        int n = nbase + g * 4 + (j >> 1);
        if (n < N_NODES) out[n * 2 + (j & 1)] = res[j] + b2[j & 1];
    }
}

// ----------------------------------------------------------------
extern "C" void kernel_launch(void* const* d_in, const int* in_sizes, int n_in,
                              void* d_out, int out_size, void* d_ws, size_t ws_size,
                              hipStream_t stream) {
    const int* x = (const int*)d_in[0];
    const int* src = (const int*)d_in[1];
    const int* dst = (const int*)d_in[2];
    const float* snorm_n = (const float*)d_in[3];
    const float* embed = (const float*)d_in[5];
    const float* Ws[3] = {(const float*)d_in[6], (const float*)d_in[11], (const float*)d_in[16]};
    const float* als[3] = {(const float*)d_in[7], (const float*)d_in[12], (const float*)d_in[17]};
    const float* ars[3] = {(const float*)d_in[8], (const float*)d_in[13], (const float*)d_in[18]};
    const float* gms[3] = {(const float*)d_in[9], (const float*)d_in[14], (const float*)d_in[19]};
    const float* bts[3] = {(const float*)d_in[10], (const float*)d_in[15], (const float*)d_in[20]};
    const float* cls1_w = (const float*)d_in[21];
    const float* cls1_b = (const float*)d_in[22];
    const float* cls2_w = (const float*)d_in[23];
    const float* cls2_b = (const float*)d_in[24];
    float* out = (float*)d_out;

    char* ws = (char*)d_ws;
    size_t off = 0;
    auto alloc = [&](size_t bytes) {
        void* p = ws + off;
        off = (off + bytes + 255) & ~(size_t)255;
        return p;
    };
    float* h = (float*)alloc((size_t)N_NODES * HDIM * 4);
    __half* feat_h = (__half*)alloc((size_t)N_NODES * HDIM * 2);
    float* el = (float*)alloc((size_t)N_NODES * 4 * 4);
    float* er = (float*)alloc((size_t)N_NODES * 4 * 4);
    int* rowstart = (int*)alloc((size_t)(N_NODES + 1) * 4);
    int* esrc = (int*)alloc((size_t)N_EDGES * 4);
    int* g_cursor = (int*)alloc((size_t)NB2 * 4);
    double* bn_sums = (double*)alloc(256 * 8);
    float* bn_scale = (float*)alloc(128 * 4);
    float* bn_shift = (float*)alloc(128 * 4);
    // bucket scratch aliases feat_h (4 MB < 12.8 MB; CSR build finishes before gemm writes it)
    unsigned* g_bucket = (unsigned*)feat_h;
    (void)ws_size; (void)in_sizes; (void)n_in; (void)out_size;

    // CSR by destination: two-phase bucket sort (contiguous reads, localized writes)
    hipMemsetAsync(g_cursor, 0, NB2 * 4, stream);
    k_partA<<<GA, 1024, 0, stream>>>(src, dst, g_cursor, g_bucket);
    k_partB<<<NB2, 1024, 0, stream>>>(g_bucket, g_cursor, rowstart, esrc);

    for (int L = 0; L < 3; L++) {
        k_gemm<<<(N_NODES + 31) / 32, 256, 0, stream>>>(h, x, embed, Ws[L], feat_h,
                                                        bn_scale, bn_shift, als[L], ars[L],
                                                        el, er, L == 0 ? 0 : 1);
        k_aggregate<<<(N_NODES + 3) / 4, 256, 0, stream>>>(feat_h, el, er, rowstart, esrc,
                                                           snorm_n, h, bn_scale, bn_shift, L);
        hipMemsetAsync(bn_sums, 0, 256 * 8, stream);
        k_bn_stats<<<1024, 128, 0, stream>>>(h, bn_sums);
        k_bn_final<<<1, 128, 0, stream>>>(bn_sums, gms[L], bts[L], bn_scale, bn_shift);
    }

    k_classifier<<<(N_NODES + 15) / 16, 256, 0, stream>>>(h, cls1_w, cls1_b, cls2_w, cls2_b,
                                                          bn_scale, bn_shift, out);
}

// Round 5
// 457.590 us; speedup vs baseline: 1.7487x; 1.1568x over previous
//
#include <hip/hip_runtime.h>
#include <hip/hip_bf16.h>
#include <hip/hip_fp16.h>
#include <math.h>

constexpr int N_NODES = 50000;
constexpr int N_EDGES = 850000;
constexpr int HDIM = 128;   // H*D

// ---------------- CSR build: two-phase bucket sort ----------------
constexpr int NB2 = 128;                                // buckets
constexpr int RANGE2 = (N_NODES + NB2 - 1) / NB2;       // 391 nodes/bucket
constexpr int CAP = 8192;                               // bucket capacity (avg 6641)
constexpr int CHUNK = 8192;                             // edges per phase-A block
constexpr int GA = (N_EDGES + CHUNK - 1) / CHUNK;       // 104 blocks

__global__ void k_partA(const int* __restrict__ src, const int* __restrict__ dst,
                        int* __restrict__ g_cursor, unsigned* __restrict__ bucket) {
    __shared__ int hist[NB2];
    int tid = threadIdx.x;
    int e0 = blockIdx.x * CHUNK;
    int e1 = min(e0 + CHUNK, N_EDGES);
    if (tid < NB2) hist[tid] = 0;
    __syncthreads();
    for (int i = e0 + tid; i < e1; i += 1024) {
        int d = dst[i];
        atomicAdd(&hist[d / RANGE2], 1);
    }
    __syncthreads();
    int base = 0;
    if (tid < NB2) base = atomicAdd(&g_cursor[tid], hist[tid]);
    __syncthreads();
    if (tid < NB2) hist[tid] = base;
    __syncthreads();
    for (int i = e0 + tid; i < e1; i += 1024) {
        int d = dst[i];
        int s = src[i];
        int b = d / RANGE2;
        int p = atomicAdd(&hist[b], 1);
        bucket[b * CAP + p] = (unsigned)s | ((unsigned)(d - b * RANGE2) << 16);
    }
}

__global__ void k_partB(const unsigned* __restrict__ bucket, const int* __restrict__ cnts,
                        int* __restrict__ rowstart, int* __restrict__ esrc) {
    __shared__ int cnt_s[NB2];
    __shared__ int hist[RANGE2];
    __shared__ int lcur[RANGE2];
    __shared__ int wsum[7];
    int b = blockIdx.x, tid = threadIdx.x;
    int lo = b * RANGE2;
    int myCount = cnts[b];
    if (tid < NB2) cnt_s[tid] = cnts[tid];
    __syncthreads();
    for (int off = 1; off < NB2; off <<= 1) {
        int t = (tid < NB2 && tid >= off) ? cnt_s[tid - off] : 0;
        __syncthreads();
        if (tid < NB2) cnt_s[tid] += t;
        __syncthreads();
    }
    int base = cnt_s[b] - myCount;
    for (int j = tid; j < RANGE2; j += 1024) hist[j] = 0;
    __syncthreads();
    const unsigned* my = bucket + (size_t)b * CAP;
    for (int i = tid; i < myCount; i += 1024) atomicAdd(&hist[my[i] >> 16], 1);
    __syncthreads();
    int v = 0;
    if (tid < 448) v = (tid < RANGE2) ? hist[tid] : 0;
    int inc = v;
    int lane = tid & 63;
#pragma unroll
    for (int off = 1; off < 64; off <<= 1) {
        int t = __shfl_up(inc, off, 64);
        if (lane >= off) inc += t;
    }
    if (tid < 448 && lane == 63) wsum[tid >> 6] = inc;
    __syncthreads();
    if (tid < RANGE2) {
        int woff = 0;
        for (int w = 0; w < (tid >> 6); w++) woff += wsum[w];
        int excl = woff + inc - v;
        lcur[tid] = excl;
        int node = lo + tid;
        if (node < N_NODES) rowstart[node] = base + excl;
    }
    if (b == 0 && tid == 0) rowstart[N_NODES] = N_EDGES;
    __syncthreads();
    for (int i = tid; i < myCount; i += 1024) {
        unsigned p = my[i];
        int pos = atomicAdd(&lcur[p >> 16], 1);
        esrc[base + pos] = (int)(p & 0xFFFFu);
    }
}

// ---------------- GEMM: feat_h = act(in) @ W (fp16 out) + fused el/er epilogue ----------------
__global__ void k_gemm(const float* __restrict__ h, const int* __restrict__ xidx,
                       const float* __restrict__ embed, const float* __restrict__ W,
                       __half* __restrict__ feat_h, const float* __restrict__ bnsc,
                       const float* __restrict__ bnsh, const float* __restrict__ al,
                       const float* __restrict__ ar, float* __restrict__ el,
                       float* __restrict__ er, int mode) {
    __shared__ __align__(16) float hsT[128][36];
    int tid = threadIdx.x;
    int nbase = blockIdx.x * 32;
    for (int i = tid; i < 32 * 128; i += 256) {
        int r = i >> 7, c = i & 127;
        int n = nbase + r;
        float v = 0.f;
        if (n < N_NODES) {
            if (mode == 0) {
                v = embed[xidx[n] * HDIM + c];
            } else {
                v = h[n * HDIM + c] * bnsc[c] + bnsh[c];
                v = (v > 0.f) ? v : expm1f(v);
            }
        }
        hsT[c][r] = v;
    }
    __syncthreads();
    int c4 = (tid & 31) * 4;
    int n4 = (tid >> 5) * 4;
    float acc[4][4] = {};
#pragma unroll 4
    for (int k = 0; k < 128; k++) {
        float4 wv4 = *reinterpret_cast<const float4*>(&W[k * HDIM + c4]);
        float4 hv4 = *reinterpret_cast<const float4*>(&hsT[k][n4]);
        float wv[4] = {wv4.x, wv4.y, wv4.z, wv4.w};
        float hh[4] = {hv4.x, hv4.y, hv4.z, hv4.w};
#pragma unroll
        for (int i = 0; i < 4; i++)
#pragma unroll
            for (int j = 0; j < 4; j++) acc[i][j] += hh[i] * wv[j];
    }
#pragma unroll
    for (int i = 0; i < 4; i++) {
        int n = nbase + n4 + i;
        if (n < N_NODES) {
            __half2* p = reinterpret_cast<__half2*>(&feat_h[n * HDIM + c4]);
            p[0] = __floats2half2_rn(acc[i][0], acc[i][1]);
            p[1] = __floats2half2_rn(acc[i][2], acc[i][3]);
        }
    }
    float4 alv = *reinterpret_cast<const float4*>(&al[c4]);
    float4 arv = *reinterpret_cast<const float4*>(&ar[c4]);
    float pl[4], pr[4];
#pragma unroll
    for (int i = 0; i < 4; i++) {
        pl[i] = acc[i][0] * alv.x + acc[i][1] * alv.y + acc[i][2] * alv.z + acc[i][3] * alv.w;
        pr[i] = acc[i][0] * arv.x + acc[i][1] * arv.y + acc[i][2] * arv.z + acc[i][3] * arv.w;
    }
#pragma unroll
    for (int off = 1; off < 8; off <<= 1)
#pragma unroll
        for (int i = 0; i < 4; i++) {
            pl[i] += __shfl_xor(pl[i], off, 64);
            pr[i] += __shfl_xor(pr[i], off, 64);
        }
    int lane = tid & 63;
    if ((lane & 7) == 0) {
        int head = c4 >> 5;
#pragma unroll
        for (int i = 0; i < 4; i++) {
            int n = nbase + n4 + i;
            if (n < N_NODES) {
                el[n * 4 + head] = pl[i];
                er[n * 4 + head] = pr[i];
            }
        }
    }
}

// ---------------- aggregation: 2 nodes per wave, LDS weight pre-phase ----------------
// Half-wave (32 lanes) owns one node; lane covers 4 dims. Pre-phase: one lane per edge
// computes all 4 head-weights into LDS; hot loop is pure gather+fma.
__global__ void k_aggregate(const __half* __restrict__ feat_h, const float* __restrict__ el,
                            const float* __restrict__ er, const int* __restrict__ rowstart,
                            const int* __restrict__ esrc, const float* __restrict__ snorm_n,
                            float* __restrict__ h, const float* __restrict__ bnsc,
                            const float* __restrict__ bnsh, int layer) {
    __shared__ int sidxbuf[4][64];
    __shared__ __align__(16) float wbuf[4][64][4];
    __shared__ int wmax[4];

    int tid = threadIdx.x;
    int wave = tid >> 6, lane = tid & 63;
    int half = lane >> 5, hl = lane & 31;
    int v = blockIdx.x * 8 + wave * 2 + half;
    bool vok = v < N_NODES;
    int vv = vok ? v : N_NODES - 1;
    int e0 = rowstart[vv];
    int deg = vok ? (rowstart[vv + 1] - e0) : 0;

    int dmax = max(deg, __shfl_xor(deg, 32, 64));
    if (lane == 0) wmax[wave] = dmax;
    __syncthreads();
    int bmax = max(max(wmax[0], wmax[1]), max(wmax[2], wmax[3]));
    int nch = (bmax + 31) >> 5;   // uniform across block -> barriers legal

    int head = hl >> 3;           // lane covers dims hl*4..hl*4+3, head = (hl*4)/32
    float4 er4 = *(const float4*)&er[vv * 4];

    float s_run = 0.f;
    float acc0 = 0.f, acc1 = 0.f, acc2 = 0.f, acc3 = 0.f;
    const __half2* fh = (const __half2*)feat_h;

    for (int c = 0; c < nch; c++) {
        int slot = c * 32 + hl;
        bool val = slot < deg;
        float w0 = 0.f, w1 = 0.f, w2 = 0.f, w3 = 0.f;
        int sidx = 0;
        if (val) {
            sidx = esrc[e0 + slot];
            float4 el4 = *(const float4*)&el[sidx * 4];
            float ex = el4.x + er4.x, ey = el4.y + er4.y;
            float ez = el4.z + er4.z, ew = el4.w + er4.w;
            ex = fmaxf(ex, 0.f) + 0.2f * fminf(ex, 0.f);
            ey = fmaxf(ey, 0.f) + 0.2f * fminf(ey, 0.f);
            ez = fmaxf(ez, 0.f) + 0.2f * fminf(ez, 0.f);
            ew = fmaxf(ew, 0.f) + 0.2f * fminf(ew, 0.f);
            w0 = __expf(ex); w1 = __expf(ey); w2 = __expf(ez); w3 = __expf(ew);
        }
        int sl = half * 32 + hl;
        sidxbuf[wave][sl] = sidx;
        wbuf[wave][sl][0] = w0; wbuf[wave][sl][1] = w1;
        wbuf[wave][sl][2] = w2; wbuf[wave][sl][3] = w3;
        __syncthreads();
        int cnt = min(32, dmax - c * 32);
        int sbase = half * 32;
#pragma unroll 2
        for (int j = 0; j < cnt; j++) {
            int si = sidxbuf[wave][sbase + j];
            float w = wbuf[wave][sbase + j][head];
            float2 r8 = *(const float2*)(fh + (size_t)si * 64 + hl * 2);
            __half2 a = *(__half2*)&r8.x, b = *(__half2*)&r8.y;
            float2 fa = __half22float2(a), fb = __half22float2(b);
            s_run += w;
            acc0 = fmaf(fa.x, w, acc0);
            acc1 = fmaf(fa.y, w, acc1);
            acc2 = fmaf(fb.x, w, acc2);
            acc3 = fmaf(fb.y, w, acc3);
        }
        __syncthreads();
    }
    if (!vok) return;
    float inv = 1.f / s_run;   // deg>=1 (self loop)
    acc0 *= inv; acc1 *= inv; acc2 *= inv; acc3 *= inv;
    int d0 = hl * 4;
    if (layer > 0) {
        float4 hr = *(const float4*)&h[(size_t)v * HDIM + d0];
        float4 sc = *(const float4*)&bnsc[d0];
        float4 sh = *(const float4*)&bnsh[d0];
        float r0 = hr.x * sc.x + sh.x; r0 = (r0 > 0.f) ? r0 : expm1f(r0);
        float r1 = hr.y * sc.y + sh.y; r1 = (r1 > 0.f) ? r1 : expm1f(r1);
        float r2 = hr.z * sc.z + sh.z; r2 = (r2 > 0.f) ? r2 : expm1f(r2);
        float r3 = hr.w * sc.w + sh.w; r3 = (r3 > 0.f) ? r3 : expm1f(r3);
        acc0 += r0; acc1 += r1; acc2 += r2; acc3 += r3;
        acc0 = (acc0 > 0.f) ? acc0 : expm1f(acc0);
        acc1 = (acc1 > 0.f) ? acc1 : expm1f(acc1);
        acc2 = (acc2 > 0.f) ? acc2 : expm1f(acc2);
        acc3 = (acc3 > 0.f) ? acc3 : expm1f(acc3);
    }
    float sn = snorm_n[v];
    *(float4*)&h[(size_t)v * HDIM + d0] = make_float4(acc0 * sn, acc1 * sn, acc2 * sn, acc3 * sn);
}

// ---------------- BatchNorm: deterministic two-level fp32 reduction ----------------
constexpr int BN_NB = 200;
constexpr int BN_ROWS = N_NODES / BN_NB;  // 250

__global__ void k_bn1(const float* __restrict__ h, float* __restrict__ part) {
    __shared__ float red[8][128][2];
    int tid = threadIdx.x;
    int c = tid & 127, g = tid >> 7;
    int r0 = blockIdx.x * BN_ROWS;
    float s = 0.f, s2 = 0.f;
    for (int r = r0 + g; r < r0 + BN_ROWS; r += 8) {
        float x = h[(size_t)r * HDIM + c];
        s += x;
        s2 = fmaf(x, x, s2);
    }
    red[g][c][0] = s;
    red[g][c][1] = s2;
    __syncthreads();
    if (tid < 128) {
        float ts = 0.f, ts2 = 0.f;
#pragma unroll
        for (int g2 = 0; g2 < 8; g2++) { ts += red[g2][tid][0]; ts2 += red[g2][tid][1]; }
        part[blockIdx.x * 256 + tid] = ts;
        part[blockIdx.x * 256 + 128 + tid] = ts2;
    }
}

__global__ void k_bn2(const float* __restrict__ part, const float* __restrict__ gamma,
                      const float* __restrict__ beta, float* __restrict__ scale,
                      float* __restrict__ shift) {
    int c = threadIdx.x;  // 128
    float s = 0.f, s2 = 0.f;
    for (int b = 0; b < BN_NB; b++) {
        s += part[b * 256 + c];
        s2 += part[b * 256 + 128 + c];
    }
    float mu = s / N_NODES;
    float var = s2 / N_NODES - mu * mu;
    float sc = gamma[c] * rsqrtf(var + 1e-5f);
    scale[c] = sc;
    shift[c] = beta[c] - mu * sc;
}

// ---------------- classifier ----------------
__global__ void k_classifier(const float* __restrict__ h, const float* __restrict__ W1,
                             const float* __restrict__ b1, const float* __restrict__ W2,
                             const float* __restrict__ b2, const float* __restrict__ bnsc,
                             const float* __restrict__ bnsh, float* __restrict__ out) {
    __shared__ float hs[16][128];
    int tid = threadIdx.x;
    int nbase = blockIdx.x * 16;
    for (int i = tid; i < 16 * 128; i += 256) {
        int r = i >> 7, c = i & 127;
        int n = nbase + r;
        float v = 0.f;
        if (n < N_NODES) {
            v = h[n * HDIM + c] * bnsc[c] + bnsh[c];
            v = (v > 0.f) ? v : expm1f(v);
        }
        hs[r][c] = v;
    }
    __syncthreads();
    int j = tid & 63;
    int g = tid >> 6;
    float bj = b1[j];
    float acc[4] = {bj, bj, bj, bj};
    for (int k = 0; k < 128; k++) {
        float w = W1[k * 64 + j];
#pragma unroll
        for (int i = 0; i < 4; i++) acc[i] += hs[g * 4 + i][k] * w;
    }
    float w20 = W2[j * 2], w21 = W2[j * 2 + 1];
    float res[8];
#pragma unroll
    for (int i = 0; i < 4; i++) {
        float hid = fmaxf(acc[i], 0.f);
        res[2 * i] = hid * w20;
        res[2 * i + 1] = hid * w21;
    }
#pragma unroll
    for (int off = 1; off < 64; off <<= 1)
#pragma unroll
        for (int i = 0; i < 8; i++) res[i] += __shfl_xor(res[i], off, 64);
    if (j < 8) {
        int n = nbase + g * 4 + (j >> 1);
        if (n < N_NODES) out[n * 2 + (j & 1)] = res[j] + b2[j & 1];
    }
}

// ----------------------------------------------------------------
extern "C" void kernel_launch(void* const* d_in, const int* in_sizes, int n_in,
                              void* d_out, int out_size, void* d_ws, size_t ws_size,
                              hipStream_t stream) {
    const int* x = (const int*)d_in[0];
    const int* src = (const int*)d_in[1];
    const int* dst = (const int*)d_in[2];
    const float* snorm_n = (const float*)d_in[3];
    const float* embed = (const float*)d_in[5];
    const float* Ws[3] = {(const float*)d_in[6], (const float*)d_in[11], (const float*)d_in[16]};
    const float* als[3] = {(const float*)d_in[7], (const float*)d_in[12], (const float*)d_in[17]};
    const float* ars[3] = {(const float*)d_in[8], (const float*)d_in[13], (const float*)d_in[18]};
    const float* gms[3] = {(const float*)d_in[9], (const float*)d_in[14], (const float*)d_in[19]};
    const float* bts[3] = {(const float*)d_in[10], (const float*)d_in[15], (const float*)d_in[20]};
    const float* cls1_w = (const float*)d_in[21];
    const float* cls1_b = (const float*)d_in[22];
    const float* cls2_w = (const float*)d_in[23];
    const float* cls2_b = (const float*)d_in[24];
    float* out = (float*)d_out;

    char* ws = (char*)d_ws;
    size_t off = 0;
    auto alloc = [&](size_t bytes) {
        void* p = ws + off;
        off = (off + bytes + 255) & ~(size_t)255;
        return p;
    };
    float* h = (float*)alloc((size_t)N_NODES * HDIM * 4);
    __half* feat_h = (__half*)alloc((size_t)N_NODES * HDIM * 2);
    float* el = (float*)alloc((size_t)N_NODES * 4 * 4);
    float* er = (float*)alloc((size_t)N_NODES * 4 * 4);
    int* rowstart = (int*)alloc((size_t)(N_NODES + 1) * 4);
    int* esrc = (int*)alloc((size_t)N_EDGES * 4);
    int* g_cursor = (int*)alloc((size_t)NB2 * 4);
    float* bn_part = (float*)alloc((size_t)BN_NB * 256 * 4);
    float* bn_scale = (float*)alloc(128 * 4);
    float* bn_shift = (float*)alloc(128 * 4);
    unsigned* g_bucket = (unsigned*)feat_h;  // 4 MB alias; CSR build finishes before gemm
    (void)ws_size; (void)in_sizes; (void)n_in; (void)out_size;

    hipMemsetAsync(g_cursor, 0, NB2 * 4, stream);
    k_partA<<<GA, 1024, 0, stream>>>(src, dst, g_cursor, g_bucket);
    k_partB<<<NB2, 1024, 0, stream>>>(g_bucket, g_cursor, rowstart, esrc);

    for (int L = 0; L < 3; L++) {
        k_gemm<<<(N_NODES + 31) / 32, 256, 0, stream>>>(h, x, embed, Ws[L], feat_h,
                                                        bn_scale, bn_shift, als[L], ars[L],
                                                        el, er, L == 0 ? 0 : 1);
        k_aggregate<<<(N_NODES + 7) / 8, 256, 0, stream>>>(feat_h, el, er, rowstart, esrc,
                                                           snorm_n, h, bn_scale, bn_shift, L);
        k_bn1<<<BN_NB, 1024, 0, stream>>>(h, bn_part);
        k_bn2<<<1, 128, 0, stream>>>(bn_part, gms[L], bts[L], bn_scale, bn_shift);
    }

    k_classifier<<<(N_NODES + 15) / 16, 256, 0, stream>>>(h, cls1_w, cls1_b, cls2_w, cls2_b,
                                                          bn_scale, bn_shift, out);
}